// Round 1
// baseline (5677.951 us; speedup 1.0000x reference)
//
#include <hip/hip_runtime.h>

#define B_   64
#define T_   512
#define NE   1024
#define ND   512

// ---------------- ws layout (floats) ----------------
// h[2][64][1024]   : 0      .. 131072
// th[2][64][1024]  : 131072 .. 262144
// last_enc[64][1024]: 262144 .. 327680
#define WS_H0    0
#define WS_H1    65536
#define WS_TH0   131072
#define WS_TH1   196608
#define WS_LAST  262144
#define WS_FLOATS 327680

// Zero the recurrent state + capture buffer (d_ws is poisoned, not re-poisoned
// between replays, so every call must re-init).
__global__ __launch_bounds__(256) void init_ws(float4* __restrict__ ws4) {
    int i = blockIdx.x * 256 + threadIdx.x;           // 81920 float4 = 327680 floats
    ws4[i] = make_float4(0.f, 0.f, 0.f, 0.f);
}

// One encoder step: h_{t+1} = 0.9*h_t + 0.1*( tanh(h_t) @ J.T + drive_t )
// grid = 256 blocks = 8 batch-groups x 32 neuron-groups
// block = 512 threads: (khalf 2) x (nl 32) x (bl 8); 2-way K split reduced in LDS
__global__ __launch_bounds__(512)
void enc_step(const float* __restrict__ hcur, const float* __restrict__ thcur,
              float* __restrict__ hnxt, float* __restrict__ thnxt,
              float* __restrict__ last_enc,
              const float* __restrict__ J,
              const float* __restrict__ noise,
              const float* __restrict__ X,
              const float* __restrict__ W_in,
              const float* __restrict__ in_s,
              const int* __restrict__ Batch_T,
              int t)
{
    __shared__ float th_s[8 * 1032];   // 8 batches x 1024, rows padded +8 floats
    __shared__ float red[256];

    const int bg = blockIdx.x >> 5;    // 0..7   (8 batches each)
    const int ng = blockIdx.x & 31;    // 0..31  (32 neurons each)
    const int tid = threadIdx.x;

    // stage tanh(h) for this block's 8 batches: 2048 float4 loads, coalesced
    {
        const float4* src = (const float4*)(thcur + (size_t)bg * 8 * NE);
        for (int i = tid; i < 2048; i += 512) {
            const int row = i >> 8;          // 256 float4 per row
            const int col = i & 255;
            float4 v = src[row * 256 + col];
            *(float4*)&th_s[row * 1032 + col * 4] = v;
        }
    }
    __syncthreads();

    const int khalf = tid >> 8;        // 0..1
    const int rem   = tid & 255;
    const int bl    = rem & 7;         // batch within group
    const int nl    = rem >> 3;        // neuron within group (0..31)
    const int b     = bg * 8 + bl;
    const int n     = ng * 32 + nl;

    const float* __restrict__ Jrow = J + (size_t)n * NE + khalf * 512;
    const float* __restrict__ trow = th_s + bl * 1032 + khalf * 512;

    float acc = 0.f;
    #pragma unroll 8
    for (int k = 0; k < 512; k += 4) {
        float4 jv = *(const float4*)(Jrow + k);
        float4 tv = *(const float4*)(trow + k);
        acc = fmaf(jv.x, tv.x, acc);
        acc = fmaf(jv.y, tv.y, acc);
        acc = fmaf(jv.z, tv.z, acc);
        acc = fmaf(jv.w, tv.w, acc);
    }

    if (khalf == 1) red[rem] = acc;
    __syncthreads();

    if (khalf == 0) {
        acc += red[rem];
        // drive = noise + (x * in_strength) @ W_in.T
        const float x0 = X[((size_t)b * T_ + t) * 2 + 0] * in_s[0];
        const float x1 = X[((size_t)b * T_ + t) * 2 + 1] * in_s[1];
        const float drive = noise[((size_t)b * T_ + t) * NE + n]
                          + x0 * W_in[n * 2 + 0] + x1 * W_in[n * 2 + 1];
        const float hprev = hcur[(size_t)b * NE + n];
        const float hnew  = 0.9f * hprev + 0.1f * (acc + drive);
        hnxt[(size_t)b * NE + n]  = hnew;
        thnxt[(size_t)b * NE + n] = tanhf(hnew);
        if (Batch_T[b] == t + 1) last_enc[(size_t)b * NE + n] = hnew;
    }
}

// last_dec[b][m] = tanh(last_enc[b]) @ W.T + b_W  -> d_out dec_traj slot 0
// grid 64 (one block per batch), 256 threads = 4 waves, wave-per-output-row
__global__ __launch_bounds__(256)
void wproj(const float* __restrict__ last_enc,
           const float* __restrict__ W,
           const float* __restrict__ bW,
           float* __restrict__ dec_traj)
{
    __shared__ float tl[NE];
    const int b = blockIdx.x;
    for (int k = threadIdx.x; k < NE; k += 256)
        tl[k] = tanhf(last_enc[(size_t)b * NE + k]);
    __syncthreads();

    const int wave = threadIdx.x >> 6;
    const int lane = threadIdx.x & 63;
    for (int m = wave; m < ND; m += 4) {
        const float4* Wr = (const float4*)(W + (size_t)m * NE);
        float acc = 0.f;
        #pragma unroll
        for (int it = 0; it < 4; ++it) {
            float4 wv = Wr[lane + it * 64];
            const float* tp = &tl[(lane + it * 64) * 4];
            acc = fmaf(wv.x, tp[0], acc);
            acc = fmaf(wv.y, tp[1], acc);
            acc = fmaf(wv.z, tp[2], acc);
            acc = fmaf(wv.w, tp[3], acc);
        }
        acc += __shfl_down(acc, 32);
        acc += __shfl_down(acc, 16);
        acc += __shfl_down(acc, 8);
        acc += __shfl_down(acc, 4);
        acc += __shfl_down(acc, 2);
        acc += __shfl_down(acc, 1);
        if (lane == 0)
            dec_traj[(size_t)b * 4 * ND + m] = acc + bW[m];
    }
}

// decoder step s: dec_traj[b][s] = dec_traj[b][s-1] @ Q.T
__global__ __launch_bounds__(256)
void dec_step(const float* __restrict__ Q, float* __restrict__ dec_traj, int s)
{
    __shared__ float prev[ND];
    const int b = blockIdx.x;
    const float* pin = dec_traj + (size_t)b * 4 * ND + (size_t)(s - 1) * ND;
    for (int k = threadIdx.x; k < ND; k += 256) prev[k] = pin[k];
    __syncthreads();

    const int wave = threadIdx.x >> 6;
    const int lane = threadIdx.x & 63;
    for (int m = wave; m < ND; m += 4) {
        const float4* Qr = (const float4*)(Q + (size_t)m * ND);
        float acc = 0.f;
        #pragma unroll
        for (int it = 0; it < 2; ++it) {
            float4 qv = Qr[lane + it * 64];
            const float* tp = &prev[(lane + it * 64) * 4];
            acc = fmaf(qv.x, tp[0], acc);
            acc = fmaf(qv.y, tp[1], acc);
            acc = fmaf(qv.z, tp[2], acc);
            acc = fmaf(qv.w, tp[3], acc);
        }
        acc += __shfl_down(acc, 32);
        acc += __shfl_down(acc, 16);
        acc += __shfl_down(acc, 8);
        acc += __shfl_down(acc, 4);
        acc += __shfl_down(acc, 2);
        acc += __shfl_down(acc, 1);
        if (lane == 0)
            dec_traj[(size_t)b * 4 * ND + (size_t)s * ND + m] = acc;
    }
}

// Output[b][s][o] = out_strength[o] * dot(dec_traj[b][s], W_out[o])
// grid 64, block 256 = 4 waves; wave = s, each wave computes both outputs
__global__ __launch_bounds__(256)
void out_proj(const float* __restrict__ dec_traj,
              const float* __restrict__ W_out,
              const float* __restrict__ out_s,
              float* __restrict__ Out)
{
    const int b = blockIdx.x;
    const int s = threadIdx.x >> 6;
    const int lane = threadIdx.x & 63;
    const float4* dp = (const float4*)(dec_traj + (size_t)b * 4 * ND + (size_t)s * ND);
    const float4* w0 = (const float4*)(W_out);
    const float4* w1 = (const float4*)(W_out + ND);
    float a0 = 0.f, a1 = 0.f;
    #pragma unroll
    for (int it = 0; it < 2; ++it) {
        float4 v  = dp[lane + it * 64];
        float4 u0 = w0[lane + it * 64];
        float4 u1 = w1[lane + it * 64];
        a0 = fmaf(v.x, u0.x, fmaf(v.y, u0.y, fmaf(v.z, u0.z, fmaf(v.w, u0.w, a0))));
        a1 = fmaf(v.x, u1.x, fmaf(v.y, u1.y, fmaf(v.z, u1.z, fmaf(v.w, u1.w, a1))));
    }
    for (int off = 32; off; off >>= 1) {
        a0 += __shfl_down(a0, off);
        a1 += __shfl_down(a1, off);
    }
    if (lane == 0) {
        Out[(size_t)b * 8 + s * 2 + 0] = out_s[0] * a0;
        Out[(size_t)b * 8 + s * 2 + 1] = out_s[1] * a1;
    }
}

extern "C" void kernel_launch(void* const* d_in, const int* in_sizes, int n_in,
                              void* d_out, int out_size, void* d_ws, size_t ws_size,
                              hipStream_t stream) {
    const float* X      = (const float*)d_in[0];   // (64,512,2)
    const float* noise  = (const float*)d_in[1];   // (64,512,1024)
    const float* W_in   = (const float*)d_in[2];   // (1024,2)
    const float* J      = (const float*)d_in[3];   // (1024,1024)
    const float* W      = (const float*)d_in[4];   // (512,1024)
    const float* bW     = (const float*)d_in[5];   // (512)
    const float* Q      = (const float*)d_in[6];   // (512,512)
    const float* W_out  = (const float*)d_in[7];   // (2,512)
    const float* in_s   = (const float*)d_in[8];   // (2)
    const float* out_s  = (const float*)d_in[9];   // (2)
    const int*   BT     = (const int*)d_in[10];    // (64)
    // d_in[11] = decoder_steps (==3, fixed)

    float* ws = (float*)d_ws;                      // needs 327680 floats = 1.25 MB
    float* h[2]  = {ws + WS_H0,  ws + WS_H1};
    float* th[2] = {ws + WS_TH0, ws + WS_TH1};
    float* last  = ws + WS_LAST;

    float* out      = (float*)d_out;               // dec_traj (64,4,512) then Output (64,4,2)
    float* out_tail = out + (size_t)B_ * 4 * ND;   // offset 131072

    init_ws<<<320, 256, 0, stream>>>((float4*)ws);

    // states 1..511 cover all Batch_T in [0,511]; Batch_T==0 handled by init zeros
    for (int t = 0; t < T_ - 1; ++t)
        enc_step<<<256, 512, 0, stream>>>(h[t & 1], th[t & 1],
                                          h[(t + 1) & 1], th[(t + 1) & 1],
                                          last, J, noise, X, W_in, in_s, BT, t);

    wproj<<<B_, 256, 0, stream>>>(last, W, bW, out);
    for (int s = 1; s <= 3; ++s)
        dec_step<<<B_, 256, 0, stream>>>(Q, out, s);
    out_proj<<<B_, 256, 0, stream>>>(out, W_out, out_s, out_tail);
}